// Round 8
// baseline (680.100 us; speedup 1.0000x reference)
//
#include <hip/hip_runtime.h>
#include <math.h>

#define HID 128
#define HEADS 4
#define NEG_SLOPE 0.2f

typedef short bf16x8 __attribute__((ext_vector_type(8)));   // 8 bf16 in 4 VGPRs
typedef float f32x4 __attribute__((ext_vector_type(4)));
typedef _Float16 f16x4 __attribute__((ext_vector_type(4)));
typedef _Float16 f16x2 __attribute__((ext_vector_type(2)));

#if defined(__has_builtin)
#if __has_builtin(__builtin_amdgcn_fdot2)
#define HAVE_FDOT2 1
#endif
#endif

// ---------------- CSR build ----------------

__global__ __launch_bounds__(256) void k_zero_int(int* p, int n) {
    int i = blockIdx.x * blockDim.x + threadIdx.x;
    if (i < n) p[i] = 0;
}

__global__ __launch_bounds__(256) void k_hist(const int* __restrict__ dst, int E, int* __restrict__ counts) {
    int e = blockIdx.x * blockDim.x + threadIdx.x;
    if (e < E) atomicAdd(&counts[dst[e]], 1);
}

__global__ __launch_bounds__(256) void k_scan_block(const int* __restrict__ counts, int N,
                                                    int* __restrict__ scanout, int* __restrict__ partials) {
    __shared__ int buf[256];
    int tid = threadIdx.x;
    int i = blockIdx.x * 256 + tid;
    int v = (i < N) ? counts[i] : 0;
    buf[tid] = v;
    __syncthreads();
    for (int off = 1; off < 256; off <<= 1) {
        int t = (tid >= off) ? buf[tid - off] : 0;
        __syncthreads();
        buf[tid] += t;
        __syncthreads();
    }
    if (i < N) scanout[i] = buf[tid] - v;
    if (tid == 255) partials[blockIdx.x] = buf[255];
}

__global__ __launch_bounds__(256) void k_scan_part(int* __restrict__ partials, int nb) {
    __shared__ int buf[256];
    int tid = threadIdx.x;
    int v = (tid < nb) ? partials[tid] : 0;
    buf[tid] = v;
    __syncthreads();
    for (int off = 1; off < 256; off <<= 1) {
        int t = (tid >= off) ? buf[tid - off] : 0;
        __syncthreads();
        buf[tid] += t;
        __syncthreads();
    }
    if (tid < nb) partials[tid] = buf[tid] - v;
}

__global__ __launch_bounds__(256) void k_scan_add(const int* __restrict__ scanout, const int* __restrict__ partials,
                                                  int N, int E, int* __restrict__ rowptr, int* __restrict__ nextp) {
    int i = blockIdx.x * 256 + threadIdx.x;
    if (i < N) {
        int r = scanout[i] + partials[blockIdx.x];
        rowptr[i] = r;
        nextp[i] = r;
    }
    if (i == 0) rowptr[N] = E;
}

__global__ __launch_bounds__(256) void k_scatter(const int* __restrict__ src, const int* __restrict__ dst, int E,
                                                 int* __restrict__ nextp, int* __restrict__ csr_src) {
    int e = blockIdx.x * blockDim.x + threadIdx.x;
    if (e < E) {
        int d = dst[e];
        int pos = atomicAdd(&nextp[d], 1);
        csr_src[pos] = src[e];
    }
}

// ---------------- fp32 -> bf16 (hi, lo) split helpers ----------------

__device__ inline unsigned short f2bf(float f) {
    unsigned u = __float_as_uint(f);
    unsigned r = (u + 0x7FFF + ((u >> 16) & 1)) >> 16;
    return (unsigned short)r;
}
__device__ inline float bf2f(unsigned short h) {
    return __uint_as_float(((unsigned)h) << 16);
}
__device__ inline f16x2 absh2(f16x2 v) {
    unsigned u = __builtin_bit_cast(unsigned, v) & 0x7FFF7FFFu;
    return __builtin_bit_cast(f16x2, u);
}

// weight split (runs twice per launch, small)
__global__ __launch_bounds__(256) void k_tobf16(const float* __restrict__ x,
                                                unsigned short* __restrict__ hi,
                                                unsigned short* __restrict__ lo, int n) {
    int i = blockIdx.x * 256 + threadIdx.x;
    int base = i * 4;
    if (base >= n) return;
    float4 v = *(const float4*)(x + base);
    float f[4] = {v.x, v.y, v.z, v.w};
    ushort4 h, l;
    unsigned short hh[4], ll[4];
    #pragma unroll
    for (int q = 0; q < 4; q++) {
        unsigned short a = f2bf(f[q]);
        hh[q] = a;
        ll[q] = f2bf(f[q] - bf2f(a));
    }
    h.x = hh[0]; h.y = hh[1]; h.z = hh[2]; h.w = hh[3];
    l.x = ll[0]; l.y = ll[1]; l.z = ll[2]; l.w = ll[3];
    *(ushort4*)(hi + base) = h;
    *(ushort4*)(lo + base) = l;
}

// ---------------- MFMA linear, LDS-resident W ----------------
// Split-precision: x*W ~= xh*Wh + xh*Wl + xl*Wh (bf16 MFMA, fp32 accumulate).
// blockIdx.y: 0 -> xlh = x@Wl.T+bl ; 1 -> xrh = x@Wr.T+br (both fp16: they
// only feed the attn edge math). Input x is the bf16 hi/lo ping-pong pair.

__global__ __launch_bounds__(512) void k_linear_mfma(
        const unsigned short* __restrict__ xhi, const unsigned short* __restrict__ xlo,
        const unsigned short* __restrict__ whiL, const unsigned short* __restrict__ wloL,
        const unsigned short* __restrict__ whiR, const unsigned short* __restrict__ wloR,
        const float* __restrict__ bl, const float* __restrict__ br,
        _Float16* __restrict__ xlh, _Float16* __restrict__ xrh, int N) {
    __shared__ unsigned short ldsh[16384];   // 32 KB: W hi, swizzled
    __shared__ unsigned short ldsl[16384];   // 32 KB: W lo, swizzled
    const int t   = threadIdx.x;
    const int mat = blockIdx.y;
    const unsigned short* Wh = mat ? whiR : whiL;
    const unsigned short* Wo = mat ? wloR : wloL;

    for (int g = t; g < 2048; g += 512) {
        int r = g >> 4, cc = g & 15;
        int dsto = r * 128 + ((cc ^ (r & 7)) << 3);      // ushort units
        *(float4*)&ldsh[dsto] = *(const float4*)(Wh + g * 8);
        *(float4*)&ldsl[dsto] = *(const float4*)(Wo + g * 8);
    }
    __syncthreads();

    const int wave = t >> 6;
    const int lane = t & 63;
    const int l16  = lane & 15;
    const int quad = lane >> 4;
    const int n0   = blockIdx.x * 128 + wave * 16;

    int arow = n0 + l16;
    if (arow >= N) arow = N - 1;       // clamp loads; stores guarded below

    f32x4 acc[8];
    #pragma unroll
    for (int s = 0; s < 8; s++) acc[s] = (f32x4){0.f, 0.f, 0.f, 0.f};

    #pragma unroll
    for (int k0 = 0; k0 < HID; k0 += 32) {
        const int aoff = arow * HID + k0 + quad * 8;
        bf16x8 ahi = *(const bf16x8*)(xhi + aoff);
        bf16x8 alo = *(const bf16x8*)(xlo + aoff);
        const int cc = (k0 >> 3) + quad;
        #pragma unroll
        for (int s = 0; s < 8; s++) {
            const int row = s * 16 + l16;
            const int off = row * 128 + ((cc ^ (l16 & 7)) << 3);
            bf16x8 bhi = *(const bf16x8*)&ldsh[off];
            bf16x8 blo = *(const bf16x8*)&ldsl[off];
            acc[s] = __builtin_amdgcn_mfma_f32_16x16x32_bf16(ahi, bhi, acc[s], 0, 0, 0);
            acc[s] = __builtin_amdgcn_mfma_f32_16x16x32_bf16(ahi, blo, acc[s], 0, 0, 0);
            acc[s] = __builtin_amdgcn_mfma_f32_16x16x32_bf16(alo, bhi, acc[s], 0, 0, 0);
        }
    }

    const float* bias = mat ? br : bl;
    _Float16* dst = mat ? xrh : xlh;
    #pragma unroll
    for (int s = 0; s < 8; s++) {
        int col = s * 16 + l16;
        float bv = bias[col];
        #pragma unroll
        for (int r = 0; r < 4; r++) {
            int node = n0 + quad * 4 + r;
            if (node < N) dst[(size_t)node * HID + col] = (_Float16)(acc[s][r] + bv);
        }
    }
}

// ---------------- Fused attention: wave per node, 2 edge streams ----------------
// All-fp16 edge math (packed adds, leaky(u)=0.6u+0.4|u|, v_dot2 att-dot),
// depth-4 gather prefetch + 1-ahead index prefetch (8 loads in flight/wave).
// No max-subtraction (|logit| <~ 3 << 88). Residual reconstructed from the
// bf16 hi/lo split; epilogue writes next layer's hi/lo (ping-pong) or,
// for the last layer, fp32 out.

__global__ __launch_bounds__(256) void k_attn(const _Float16* __restrict__ xlh, const _Float16* __restrict__ xrh,
                                              const int* __restrict__ rowptr, const int* __restrict__ csr_src,
                                              const float* __restrict__ att, const float* __restrict__ bias,
                                              const unsigned short* __restrict__ resH, const unsigned short* __restrict__ resL,
                                              unsigned short* __restrict__ outH, unsigned short* __restrict__ outL,
                                              float* __restrict__ out,
                                              int add_res, int want_split, int N) {
    const int wave = threadIdx.x >> 6;
    const int lane = threadIdx.x & 63;
    const int sub  = lane >> 5;          // edge stream 0/1
    const int l32  = lane & 31;          // channels [4*l32, 4*l32+4); head = l32>>3
    const int n = blockIdx.x * 4 + wave;
    if (n >= N) return;

    const float4 a4 = *(const float4*)(att + 4 * l32);
    const f16x2 att01 = (f16x2){(_Float16)a4.x, (_Float16)a4.y};
    const f16x2 att23 = (f16x2){(_Float16)a4.z, (_Float16)a4.w};
    const f16x4 xrv = *(const f16x4*)(xrh + (size_t)n * HID + 4 * l32);
    const f16x2 xr01 = __builtin_shufflevector(xrv, xrv, 0, 1);
    const f16x2 xr23 = __builtin_shufflevector(xrv, xrv, 2, 3);
    const f16x2 k06 = (f16x2){(_Float16)0.6f, (_Float16)0.6f};
    const f16x2 k04 = (f16x2){(_Float16)0.4f, (_Float16)0.4f};
    const int s0 = rowptr[n], s1 = rowptr[n + 1];

    float den = 0.f;
    float4 acc = make_float4(0.f, 0.f, 0.f, 0.f);

    int j = s0 + sub;
    if (j < s1) {
        const int last = s1 - 1;
        f16x4 p0, p1, p2, p3;
        int i4;
        p0 = *(const f16x4*)(xlh + (size_t)csr_src[min(j,     last)] * HID + 4 * l32);
        p1 = *(const f16x4*)(xlh + (size_t)csr_src[min(j + 2, last)] * HID + 4 * l32);
        p2 = *(const f16x4*)(xlh + (size_t)csr_src[min(j + 4, last)] * HID + 4 * l32);
        p3 = *(const f16x4*)(xlh + (size_t)csr_src[min(j + 6, last)] * HID + 4 * l32);
        i4 = csr_src[min(j + 8, last)];
        while (j < s1) {
            f16x4 cur = p0;
            p0 = p1; p1 = p2; p2 = p3;
            p3 = *(const f16x4*)(xlh + (size_t)i4 * HID + 4 * l32);
            i4 = csr_src[min(j + 10, last)];

            f16x2 c01 = __builtin_shufflevector(cur, cur, 0, 1);
            f16x2 c23 = __builtin_shufflevector(cur, cur, 2, 3);
            f16x2 u01 = c01 + xr01;
            f16x2 u23 = c23 + xr23;
            f16x2 l01 = u01 * k06 + absh2(u01) * k04;   // leaky_relu, packed
            f16x2 l23 = u23 * k06 + absh2(u23) * k04;
#ifdef HAVE_FDOT2
            float p = __builtin_amdgcn_fdot2(l01, att01, 0.f, false);
            p = __builtin_amdgcn_fdot2(l23, att23, p, false);
#else
            float p = (float)l01[0] * (float)att01[0] + (float)l01[1] * (float)att01[1]
                    + (float)l23[0] * (float)att23[0] + (float)l23[1] * (float)att23[1];
#endif
            p += __shfl_xor(p, 1);           // reduce 8-lane head group
            p += __shfl_xor(p, 2);
            p += __shfl_xor(p, 4);
            float w = __expf(p);
            den += w;
            acc.x += w * (float)cur[0];
            acc.y += w * (float)cur[1];
            acc.z += w * (float)cur[2];
            acc.w += w * (float)cur[3];
            j += 2;
        }
    }

    // merge the two streams across the half-wave boundary
    den   += __shfl_xor(den, 32);
    acc.x += __shfl_xor(acc.x, 32);
    acc.y += __shfl_xor(acc.y, 32);
    acc.z += __shfl_xor(acc.z, 32);
    acc.w += __shfl_xor(acc.w, 32);

    if (sub == 0) {
        float4 b4 = *(const float4*)(bias + 4 * l32);
        float inv = (den > 0.f) ? 1.f / den : 0.f;
        float4 v;
        v.x = fmaxf(acc.x * inv + b4.x, 0.f);
        v.y = fmaxf(acc.y * inv + b4.y, 0.f);
        v.z = fmaxf(acc.z * inv + b4.z, 0.f);
        v.w = fmaxf(acc.w * inv + b4.w, 0.f);
        if (add_res) {
            ushort4 rh = *(const ushort4*)(resH + (size_t)n * HID + 4 * l32);
            ushort4 rl = *(const ushort4*)(resL + (size_t)n * HID + 4 * l32);
            v.x += bf2f(rh.x) + bf2f(rl.x);
            v.y += bf2f(rh.y) + bf2f(rl.y);
            v.z += bf2f(rh.z) + bf2f(rl.z);
            v.w += bf2f(rh.w) + bf2f(rl.w);
        }
        if (want_split) {
            float f[4] = {v.x, v.y, v.z, v.w};
            unsigned short hh[4], ll[4];
            #pragma unroll
            for (int q = 0; q < 4; q++) {
                unsigned short a = f2bf(f[q]);
                hh[q] = a;
                ll[q] = f2bf(f[q] - bf2f(a));
            }
            ushort4 h4, l4;
            h4.x = hh[0]; h4.y = hh[1]; h4.z = hh[2]; h4.w = hh[3];
            l4.x = ll[0]; l4.y = ll[1]; l4.z = ll[2]; l4.w = ll[3];
            *(ushort4*)(outH + (size_t)n * HID + 4 * l32) = h4;
            *(ushort4*)(outL + (size_t)n * HID + 4 * l32) = l4;
        } else {
            *(float4*)(out + (size_t)n * HID + 4 * l32) = v;
        }
    }
}

// ---------------- Embedding: x = relu(nf @ W_emb.T + b_emb) -> bf16 hi/lo ----------------

__global__ __launch_bounds__(128) void k_embed(const float* __restrict__ nf, const float* __restrict__ W,
                                               const float* __restrict__ b,
                                               unsigned short* __restrict__ xhi, unsigned short* __restrict__ xlo,
                                               int N) {
    __shared__ float f[11];
    int n = blockIdx.x;
    int h = threadIdx.x;
    if (h < 11) f[h] = nf[(size_t)n * 11 + h];
    __syncthreads();
    float acc = b[h];
    #pragma unroll
    for (int k = 0; k < 11; k++) acc += f[k] * W[h * 11 + k];
    float v = fmaxf(acc, 0.f);
    unsigned short hh = f2bf(v);
    xhi[(size_t)n * HID + h] = hh;
    xlo[(size_t)n * HID + h] = f2bf(v - bf2f(hh));
}

// ---------------- Graph readout: mean + max over nodes ----------------

__global__ __launch_bounds__(128) void k_reduce1(const float* __restrict__ x, int N,
                                                 float* __restrict__ psum, float* __restrict__ pmax) {
    int b = blockIdx.x;
    int h = threadIdx.x;
    int per = (N + gridDim.x - 1) / gridDim.x;
    int n0 = b * per, n1 = min(N, n0 + per);
    float s = 0.f, m = -INFINITY;
    for (int n = n0; n < n1; n++) {
        float v = x[(size_t)n * HID + h];
        s += v;
        m = fmaxf(m, v);
    }
    psum[b * HID + h] = s;
    pmax[b * HID + h] = m;
}

__global__ __launch_bounds__(128) void k_reduce2(const float* __restrict__ psum, const float* __restrict__ pmax,
                                                 int nb, float* __restrict__ out, float invN) {
    int h = threadIdx.x;
    float s = 0.f, m = -INFINITY;
    for (int b = 0; b < nb; b++) {
        s += psum[b * HID + h];
        m = fmaxf(m, pmax[b * HID + h]);
    }
    out[h] = s * invN;
    out[HID + h] = m;
}

// ---------------- Launch ----------------

extern "C" void kernel_launch(void* const* d_in, const int* in_sizes, int n_in,
                              void* d_out, int out_size, void* d_ws, size_t ws_size,
                              hipStream_t stream) {
    const float* nf    = (const float*)d_in[0];
    const int*   ei    = (const int*)d_in[1];
    const float* W_emb = (const float*)d_in[3];
    const float* b_emb = (const float*)d_in[4];
    const float* Wl    = (const float*)d_in[5];
    const float* bl    = (const float*)d_in[6];
    const float* Wr    = (const float*)d_in[7];
    const float* br    = (const float*)d_in[8];
    const float* att   = (const float*)d_in[9];
    const float* bias  = (const float*)d_in[10];

    const int N = in_sizes[0] / 11;
    const int E = in_sizes[1] / 2;
    const int* src = ei;
    const int* dst = ei + E;

    float* out  = (float*)d_out;
    float* xout = out + 2 * HID;

    // workspace carve-up
    char* w = (char*)d_ws;
    _Float16* xlh   = (_Float16*)w; w += (size_t)N * HID * 2;
    _Float16* xrh   = (_Float16*)w; w += (size_t)N * HID * 2;
    unsigned short* hA = (unsigned short*)w; w += (size_t)N * HID * 2;
    unsigned short* lA = (unsigned short*)w; w += (size_t)N * HID * 2;
    unsigned short* hB = (unsigned short*)w; w += (size_t)N * HID * 2;
    unsigned short* lB = (unsigned short*)w; w += (size_t)N * HID * 2;
    unsigned short* whiL = (unsigned short*)w; w += (size_t)4 * HID * HID * 2;
    unsigned short* wloL = (unsigned short*)w; w += (size_t)4 * HID * HID * 2;
    unsigned short* whiR = (unsigned short*)w; w += (size_t)4 * HID * HID * 2;
    unsigned short* wloR = (unsigned short*)w; w += (size_t)4 * HID * HID * 2;
    int*   counts   = (int*)w;   w += (size_t)N * 4;
    int*   scanout  = (int*)w;   w += (size_t)N * 4;
    int*   rowptr   = (int*)w;   w += (size_t)(N + 1) * 4;
    int*   nextp    = (int*)w;   w += (size_t)N * 4;
    int*   partials = (int*)w;   w += (size_t)256 * 4;
    int*   csr_src  = (int*)w;   w += (size_t)E * 4;
    float* psum     = (float*)w; w += (size_t)256 * HID * 4;
    float* pmax     = (float*)w; w += (size_t)256 * HID * 4;

    const int nb = (N + 255) / 256;
    const int nW = 4 * HID * HID;

    // weight bf16 split (once per launch)
    k_tobf16<<<(nW / 4 + 255) / 256, 256, 0, stream>>>(Wl, whiL, wloL, nW);
    k_tobf16<<<(nW / 4 + 255) / 256, 256, 0, stream>>>(Wr, whiR, wloR, nW);

    // CSR build
    k_zero_int<<<nb, 256, 0, stream>>>(counts, N);
    k_hist<<<(E + 255) / 256, 256, 0, stream>>>(dst, E, counts);
    k_scan_block<<<nb, 256, 0, stream>>>(counts, N, scanout, partials);
    k_scan_part<<<1, 256, 0, stream>>>(partials, nb);
    k_scan_add<<<nb, 256, 0, stream>>>(scanout, partials, N, E, rowptr, nextp);
    k_scatter<<<(E + 255) / 256, 256, 0, stream>>>(src, dst, E, nextp, csr_src);

    // embedding -> bf16 hi/lo (buffer A)
    k_embed<<<N, 128, 0, stream>>>(nf, W_emb, b_emb, hA, lA, N);

    dim3 lgrid((N + 127) / 128, 2);
    for (int i = 0; i < 4; i++) {
        // ping-pong: even layers read A write B, odd layers read B write A
        const unsigned short* inH = (i & 1) ? hB : hA;
        const unsigned short* inL = (i & 1) ? lB : lA;
        unsigned short* oH = (i & 1) ? hA : hB;
        unsigned short* oL = (i & 1) ? lA : lB;
        k_linear_mfma<<<lgrid, 512, 0, stream>>>(inH, inL,
                                                 whiL + (size_t)i * HID * HID, wloL + (size_t)i * HID * HID,
                                                 whiR + (size_t)i * HID * HID, wloR + (size_t)i * HID * HID,
                                                 bl + i * HID, br + i * HID, xlh, xrh, N);
        k_attn<<<(N + 3) / 4, 256, 0, stream>>>(xlh, xrh, rowptr, csr_src,
                                                att + i * HEADS * 32, bias + i * HID,
                                                inH, inL, oH, oL, xout,
                                                i > 0 ? 1 : 0, i < 3 ? 1 : 0, N);
    }

    k_reduce1<<<256, 128, 0, stream>>>(xout, N, psum, pmax);
    k_reduce2<<<1, 128, 0, stream>>>(psum, pmax, 256, out, 1.0f / N);
}

// Round 9
// 603.521 us; speedup vs baseline: 1.1269x; 1.1269x over previous
//
#include <hip/hip_runtime.h>
#include <math.h>

#define HID 128
#define HEADS 4
#define NEG_SLOPE 0.2f

typedef short bf16x8 __attribute__((ext_vector_type(8)));   // 8 bf16 in 4 VGPRs
typedef float f32x4 __attribute__((ext_vector_type(4)));
typedef _Float16 f16x8 __attribute__((ext_vector_type(8)));
typedef _Float16 f16x2 __attribute__((ext_vector_type(2)));

#if defined(__has_builtin)
#if __has_builtin(__builtin_amdgcn_fdot2)
#define HAVE_FDOT2 1
#endif
#endif

// ---------------- CSR build ----------------

__global__ __launch_bounds__(256) void k_zero_int(int* p, int n) {
    int i = blockIdx.x * blockDim.x + threadIdx.x;
    if (i < n) p[i] = 0;
}

__global__ __launch_bounds__(256) void k_hist(const int* __restrict__ dst, int E, int* __restrict__ counts) {
    int e = blockIdx.x * blockDim.x + threadIdx.x;
    if (e < E) atomicAdd(&counts[dst[e]], 1);
}

__global__ __launch_bounds__(256) void k_scan_block(const int* __restrict__ counts, int N,
                                                    int* __restrict__ scanout, int* __restrict__ partials) {
    __shared__ int buf[256];
    int tid = threadIdx.x;
    int i = blockIdx.x * 256 + tid;
    int v = (i < N) ? counts[i] : 0;
    buf[tid] = v;
    __syncthreads();
    for (int off = 1; off < 256; off <<= 1) {
        int t = (tid >= off) ? buf[tid - off] : 0;
        __syncthreads();
        buf[tid] += t;
        __syncthreads();
    }
    if (i < N) scanout[i] = buf[tid] - v;
    if (tid == 255) partials[blockIdx.x] = buf[255];
}

__global__ __launch_bounds__(256) void k_scan_part(int* __restrict__ partials, int nb) {
    __shared__ int buf[256];
    int tid = threadIdx.x;
    int v = (tid < nb) ? partials[tid] : 0;
    buf[tid] = v;
    __syncthreads();
    for (int off = 1; off < 256; off <<= 1) {
        int t = (tid >= off) ? buf[tid - off] : 0;
        __syncthreads();
        buf[tid] += t;
        __syncthreads();
    }
    if (tid < nb) partials[tid] = buf[tid] - v;
}

__global__ __launch_bounds__(256) void k_scan_add(const int* __restrict__ scanout, const int* __restrict__ partials,
                                                  int N, int E, int* __restrict__ rowptr, int* __restrict__ nextp) {
    int i = blockIdx.x * 256 + threadIdx.x;
    if (i < N) {
        int r = scanout[i] + partials[blockIdx.x];
        rowptr[i] = r;
        nextp[i] = r;
    }
    if (i == 0) rowptr[N] = E;
}

// stores BYTE offsets (src * HID * 2) so the attn hot loop does base+off only
__global__ __launch_bounds__(256) void k_scatter(const int* __restrict__ src, const int* __restrict__ dst, int E,
                                                 int* __restrict__ nextp, int* __restrict__ csr_off) {
    int e = blockIdx.x * blockDim.x + threadIdx.x;
    if (e < E) {
        int d = dst[e];
        int pos = atomicAdd(&nextp[d], 1);
        csr_off[pos] = src[e] * (HID * 2);
    }
}

// ---------------- fp32 -> bf16 (hi, lo) split helpers ----------------

__device__ inline unsigned short f2bf(float f) {
    unsigned u = __float_as_uint(f);
    unsigned r = (u + 0x7FFF + ((u >> 16) & 1)) >> 16;
    return (unsigned short)r;
}
__device__ inline float bf2f(unsigned short h) {
    return __uint_as_float(((unsigned)h) << 16);
}
__device__ inline f16x2 absh2(f16x2 v) {
    unsigned u = __builtin_bit_cast(unsigned, v) & 0x7FFF7FFFu;
    return __builtin_bit_cast(f16x2, u);
}

// weight split (runs twice per launch, small)
__global__ __launch_bounds__(256) void k_tobf16(const float* __restrict__ x,
                                                unsigned short* __restrict__ hi,
                                                unsigned short* __restrict__ lo, int n) {
    int i = blockIdx.x * 256 + threadIdx.x;
    int base = i * 4;
    if (base >= n) return;
    float4 v = *(const float4*)(x + base);
    float f[4] = {v.x, v.y, v.z, v.w};
    ushort4 h, l;
    unsigned short hh[4], ll[4];
    #pragma unroll
    for (int q = 0; q < 4; q++) {
        unsigned short a = f2bf(f[q]);
        hh[q] = a;
        ll[q] = f2bf(f[q] - bf2f(a));
    }
    h.x = hh[0]; h.y = hh[1]; h.z = hh[2]; h.w = hh[3];
    l.x = ll[0]; l.y = ll[1]; l.z = ll[2]; l.w = ll[3];
    *(ushort4*)(hi + base) = h;
    *(ushort4*)(lo + base) = l;
}

// ---------------- MFMA linear, LDS-resident W ----------------
// Split-precision: x*W ~= xh*Wh + xh*Wl + xl*Wh (bf16 MFMA, fp32 accumulate).
// blockIdx.y: 0 -> xlh = x@Wl.T+bl ; 1 -> xrh = x@Wr.T+br (both fp16).

__global__ __launch_bounds__(512) void k_linear_mfma(
        const unsigned short* __restrict__ xhi, const unsigned short* __restrict__ xlo,
        const unsigned short* __restrict__ whiL, const unsigned short* __restrict__ wloL,
        const unsigned short* __restrict__ whiR, const unsigned short* __restrict__ wloR,
        const float* __restrict__ bl, const float* __restrict__ br,
        _Float16* __restrict__ xlh, _Float16* __restrict__ xrh, int N) {
    __shared__ unsigned short ldsh[16384];   // 32 KB: W hi, swizzled
    __shared__ unsigned short ldsl[16384];   // 32 KB: W lo, swizzled
    const int t   = threadIdx.x;
    const int mat = blockIdx.y;
    const unsigned short* Wh = mat ? whiR : whiL;
    const unsigned short* Wo = mat ? wloR : wloL;

    for (int g = t; g < 2048; g += 512) {
        int r = g >> 4, cc = g & 15;
        int dsto = r * 128 + ((cc ^ (r & 7)) << 3);      // ushort units
        *(float4*)&ldsh[dsto] = *(const float4*)(Wh + g * 8);
        *(float4*)&ldsl[dsto] = *(const float4*)(Wo + g * 8);
    }
    __syncthreads();

    const int wave = t >> 6;
    const int lane = t & 63;
    const int l16  = lane & 15;
    const int quad = lane >> 4;
    const int n0   = blockIdx.x * 128 + wave * 16;

    int arow = n0 + l16;
    if (arow >= N) arow = N - 1;       // clamp loads; stores guarded below

    f32x4 acc[8];
    #pragma unroll
    for (int s = 0; s < 8; s++) acc[s] = (f32x4){0.f, 0.f, 0.f, 0.f};

    #pragma unroll
    for (int k0 = 0; k0 < HID; k0 += 32) {
        const int aoff = arow * HID + k0 + quad * 8;
        bf16x8 ahi = *(const bf16x8*)(xhi + aoff);
        bf16x8 alo = *(const bf16x8*)(xlo + aoff);
        const int cc = (k0 >> 3) + quad;
        #pragma unroll
        for (int s = 0; s < 8; s++) {
            const int row = s * 16 + l16;
            const int off = row * 128 + ((cc ^ (l16 & 7)) << 3);
            bf16x8 bhi = *(const bf16x8*)&ldsh[off];
            bf16x8 blo = *(const bf16x8*)&ldsl[off];
            acc[s] = __builtin_amdgcn_mfma_f32_16x16x32_bf16(ahi, bhi, acc[s], 0, 0, 0);
            acc[s] = __builtin_amdgcn_mfma_f32_16x16x32_bf16(ahi, blo, acc[s], 0, 0, 0);
            acc[s] = __builtin_amdgcn_mfma_f32_16x16x32_bf16(alo, bhi, acc[s], 0, 0, 0);
        }
    }

    const float* bias = mat ? br : bl;
    _Float16* dst = mat ? xrh : xlh;
    #pragma unroll
    for (int s = 0; s < 8; s++) {
        int col = s * 16 + l16;
        float bv = bias[col];
        #pragma unroll
        for (int r = 0; r < 4; r++) {
            int node = n0 + quad * 4 + r;
            if (node < N) dst[(size_t)node * HID + col] = (_Float16)(acc[s][r] + bv);
        }
    }
}

// ---------------- Fused attention: wave per node, 4 edge streams ----------------
// Stream = 16 lanes, f16x8 (16 B) per lane -> one 256 B row per stream per
// iteration; ~deg/4 iterations. 4 concurrent gathers + depth-2 prefetch each
// + byte-offset indices (no 64-bit mul in the dependent chain). Head-dot:
// in-lane 8-ch dot then 2 shfl_xor (head = 4 lanes). No max-subtraction
// (|logit| <~ 3 << 88). Residual from bf16 hi/lo; epilogue writes next
// layer's hi/lo (ping-pong) or fp32 out for the last layer.

__global__ __launch_bounds__(256) void k_attn(const _Float16* __restrict__ xlh, const _Float16* __restrict__ xrh,
                                              const int* __restrict__ rowptr, const int* __restrict__ csr_off,
                                              const float* __restrict__ att, const float* __restrict__ bias,
                                              const unsigned short* __restrict__ resH, const unsigned short* __restrict__ resL,
                                              unsigned short* __restrict__ outH, unsigned short* __restrict__ outL,
                                              float* __restrict__ out,
                                              int add_res, int want_split, int N) {
    const int wave = threadIdx.x >> 6;
    const int lane = threadIdx.x & 63;
    const int strm = lane >> 4;          // edge stream 0..3
    const int l16  = lane & 15;          // channels [8*l16, 8*l16+8); head = l16>>2
    const int n = blockIdx.x * 4 + wave;
    if (n >= N) return;

    const float4 aA = *(const float4*)(att + 8 * l16);
    const float4 aB = *(const float4*)(att + 8 * l16 + 4);
    const f16x2 a0 = (f16x2){(_Float16)aA.x, (_Float16)aA.y};
    const f16x2 a1 = (f16x2){(_Float16)aA.z, (_Float16)aA.w};
    const f16x2 a2 = (f16x2){(_Float16)aB.x, (_Float16)aB.y};
    const f16x2 a3 = (f16x2){(_Float16)aB.z, (_Float16)aB.w};
    const f16x8 xrv = *(const f16x8*)(xrh + (size_t)n * HID + 8 * l16);
    const f16x2 xr0 = __builtin_shufflevector(xrv, xrv, 0, 1);
    const f16x2 xr1 = __builtin_shufflevector(xrv, xrv, 2, 3);
    const f16x2 xr2 = __builtin_shufflevector(xrv, xrv, 4, 5);
    const f16x2 xr3 = __builtin_shufflevector(xrv, xrv, 6, 7);
    const f16x2 k06 = (f16x2){(_Float16)0.6f, (_Float16)0.6f};
    const f16x2 k04 = (f16x2){(_Float16)0.4f, (_Float16)0.4f};
    const int s0 = rowptr[n], s1 = rowptr[n + 1];

    float den = 0.f;
    float acc[8];
    #pragma unroll
    for (int q = 0; q < 8; q++) acc[q] = 0.f;

    const char* xlb = (const char*)xlh + l16 * 16;  // lane's 16B slice within a row

    int j = s0 + strm;
    if (j < s1) {
        const int last = s1 - 1;
        f16x8 p0 = *(const f16x8*)(xlb + csr_off[min(j,     last)]);
        f16x8 p1 = *(const f16x8*)(xlb + csr_off[min(j + 4, last)]);
        int   o2 = csr_off[min(j + 8, last)];
        while (j < s1) {
            f16x8 cur = p0;
            p0 = p1;
            p1 = *(const f16x8*)(xlb + o2);
            o2 = csr_off[min(j + 12, last)];

            f16x2 c0 = __builtin_shufflevector(cur, cur, 0, 1);
            f16x2 c1 = __builtin_shufflevector(cur, cur, 2, 3);
            f16x2 c2 = __builtin_shufflevector(cur, cur, 4, 5);
            f16x2 c3 = __builtin_shufflevector(cur, cur, 6, 7);
            f16x2 u0 = c0 + xr0, u1 = c1 + xr1, u2 = c2 + xr2, u3 = c3 + xr3;
            f16x2 l0 = u0 * k06 + absh2(u0) * k04;   // leaky_relu, packed
            f16x2 l1 = u1 * k06 + absh2(u1) * k04;
            f16x2 l2 = u2 * k06 + absh2(u2) * k04;
            f16x2 l3 = u3 * k06 + absh2(u3) * k04;
#ifdef HAVE_FDOT2
            float p = __builtin_amdgcn_fdot2(l0, a0, 0.f, false);
            p = __builtin_amdgcn_fdot2(l1, a1, p, false);
            p = __builtin_amdgcn_fdot2(l2, a2, p, false);
            p = __builtin_amdgcn_fdot2(l3, a3, p, false);
#else
            float p = (float)l0[0] * (float)a0[0] + (float)l0[1] * (float)a0[1]
                    + (float)l1[0] * (float)a1[0] + (float)l1[1] * (float)a1[1]
                    + (float)l2[0] * (float)a2[0] + (float)l2[1] * (float)a2[1]
                    + (float)l3[0] * (float)a3[0] + (float)l3[1] * (float)a3[1];
#endif
            p += __shfl_xor(p, 1);           // reduce 4-lane head group
            p += __shfl_xor(p, 2);
            float w = __expf(p);
            den += w;
            #pragma unroll
            for (int q = 0; q < 8; q++) acc[q] += w * (float)cur[q];
            j += 4;
        }
    }

    // merge the four streams (lane stride 16/32)
    den += __shfl_xor(den, 16);
    den += __shfl_xor(den, 32);
    #pragma unroll
    for (int q = 0; q < 8; q++) {
        acc[q] += __shfl_xor(acc[q], 16);
        acc[q] += __shfl_xor(acc[q], 32);
    }

    if (strm == 0) {
        float4 bA = *(const float4*)(bias + 8 * l16);
        float4 bB = *(const float4*)(bias + 8 * l16 + 4);
        float b[8] = {bA.x, bA.y, bA.z, bA.w, bB.x, bB.y, bB.z, bB.w};
        float inv = (den > 0.f) ? 1.f / den : 0.f;
        float v[8];
        #pragma unroll
        for (int q = 0; q < 8; q++) v[q] = fmaxf(acc[q] * inv + b[q], 0.f);
        if (add_res) {
            ushort4 rh0 = *(const ushort4*)(resH + (size_t)n * HID + 8 * l16);
            ushort4 rh1 = *(const ushort4*)(resH + (size_t)n * HID + 8 * l16 + 4);
            ushort4 rl0 = *(const ushort4*)(resL + (size_t)n * HID + 8 * l16);
            ushort4 rl1 = *(const ushort4*)(resL + (size_t)n * HID + 8 * l16 + 4);
            v[0] += bf2f(rh0.x) + bf2f(rl0.x);
            v[1] += bf2f(rh0.y) + bf2f(rl0.y);
            v[2] += bf2f(rh0.z) + bf2f(rl0.z);
            v[3] += bf2f(rh0.w) + bf2f(rl0.w);
            v[4] += bf2f(rh1.x) + bf2f(rl1.x);
            v[5] += bf2f(rh1.y) + bf2f(rl1.y);
            v[6] += bf2f(rh1.z) + bf2f(rl1.z);
            v[7] += bf2f(rh1.w) + bf2f(rl1.w);
        }
        if (want_split) {
            unsigned short hh[8], ll[8];
            #pragma unroll
            for (int q = 0; q < 8; q++) {
                unsigned short a = f2bf(v[q]);
                hh[q] = a;
                ll[q] = f2bf(v[q] - bf2f(a));
            }
            ushort4 h0 = {hh[0], hh[1], hh[2], hh[3]};
            ushort4 h1 = {hh[4], hh[5], hh[6], hh[7]};
            ushort4 l0v = {ll[0], ll[1], ll[2], ll[3]};
            ushort4 l1v = {ll[4], ll[5], ll[6], ll[7]};
            *(ushort4*)(outH + (size_t)n * HID + 8 * l16)     = h0;
            *(ushort4*)(outH + (size_t)n * HID + 8 * l16 + 4) = h1;
            *(ushort4*)(outL + (size_t)n * HID + 8 * l16)     = l0v;
            *(ushort4*)(outL + (size_t)n * HID + 8 * l16 + 4) = l1v;
        } else {
            *(float4*)(out + (size_t)n * HID + 8 * l16)     = make_float4(v[0], v[1], v[2], v[3]);
            *(float4*)(out + (size_t)n * HID + 8 * l16 + 4) = make_float4(v[4], v[5], v[6], v[7]);
        }
    }
}

// ---------------- Embedding: x = relu(nf @ W_emb.T + b_emb) -> bf16 hi/lo ----------------

__global__ __launch_bounds__(128) void k_embed(const float* __restrict__ nf, const float* __restrict__ W,
                                               const float* __restrict__ b,
                                               unsigned short* __restrict__ xhi, unsigned short* __restrict__ xlo,
                                               int N) {
    __shared__ float f[11];
    int n = blockIdx.x;
    int h = threadIdx.x;
    if (h < 11) f[h] = nf[(size_t)n * 11 + h];
    __syncthreads();
    float acc = b[h];
    #pragma unroll
    for (int k = 0; k < 11; k++) acc += f[k] * W[h * 11 + k];
    float v = fmaxf(acc, 0.f);
    unsigned short hh = f2bf(v);
    xhi[(size_t)n * HID + h] = hh;
    xlo[(size_t)n * HID + h] = f2bf(v - bf2f(hh));
}

// ---------------- Graph readout: mean + max over nodes ----------------

__global__ __launch_bounds__(128) void k_reduce1(const float* __restrict__ x, int N,
                                                 float* __restrict__ psum, float* __restrict__ pmax) {
    int b = blockIdx.x;
    int h = threadIdx.x;
    int per = (N + gridDim.x - 1) / gridDim.x;
    int n0 = b * per, n1 = min(N, n0 + per);
    float s = 0.f, m = -INFINITY;
    for (int n = n0; n < n1; n++) {
        float v = x[(size_t)n * HID + h];
        s += v;
        m = fmaxf(m, v);
    }
    psum[b * HID + h] = s;
    pmax[b * HID + h] = m;
}

__global__ __launch_bounds__(128) void k_reduce2(const float* __restrict__ psum, const float* __restrict__ pmax,
                                                 int nb, float* __restrict__ out, float invN) {
    int h = threadIdx.x;
    float s = 0.f, m = -INFINITY;
    for (int b = 0; b < nb; b++) {
        s += psum[b * HID + h];
        m = fmaxf(m, pmax[b * HID + h]);
    }
    out[h] = s * invN;
    out[HID + h] = m;
}

// ---------------- Launch ----------------

extern "C" void kernel_launch(void* const* d_in, const int* in_sizes, int n_in,
                              void* d_out, int out_size, void* d_ws, size_t ws_size,
                              hipStream_t stream) {
    const float* nf    = (const float*)d_in[0];
    const int*   ei    = (const int*)d_in[1];
    const float* W_emb = (const float*)d_in[3];
    const float* b_emb = (const float*)d_in[4];
    const float* Wl    = (const float*)d_in[5];
    const float* bl    = (const float*)d_in[6];
    const float* Wr    = (const float*)d_in[7];
    const float* br    = (const float*)d_in[8];
    const float* att   = (const float*)d_in[9];
    const float* bias  = (const float*)d_in[10];

    const int N = in_sizes[0] / 11;
    const int E = in_sizes[1] / 2;
    const int* src = ei;
    const int* dst = ei + E;

    float* out  = (float*)d_out;
    float* xout = out + 2 * HID;

    // workspace carve-up
    char* w = (char*)d_ws;
    _Float16* xlh   = (_Float16*)w; w += (size_t)N * HID * 2;
    _Float16* xrh   = (_Float16*)w; w += (size_t)N * HID * 2;
    unsigned short* hA = (unsigned short*)w; w += (size_t)N * HID * 2;
    unsigned short* lA = (unsigned short*)w; w += (size_t)N * HID * 2;
    unsigned short* hB = (unsigned short*)w; w += (size_t)N * HID * 2;
    unsigned short* lB = (unsigned short*)w; w += (size_t)N * HID * 2;
    unsigned short* whiL = (unsigned short*)w; w += (size_t)4 * HID * HID * 2;
    unsigned short* wloL = (unsigned short*)w; w += (size_t)4 * HID * HID * 2;
    unsigned short* whiR = (unsigned short*)w; w += (size_t)4 * HID * HID * 2;
    unsigned short* wloR = (unsigned short*)w; w += (size_t)4 * HID * HID * 2;
    int*   counts   = (int*)w;   w += (size_t)N * 4;
    int*   scanout  = (int*)w;   w += (size_t)N * 4;
    int*   rowptr   = (int*)w;   w += (size_t)(N + 1) * 4;
    int*   nextp    = (int*)w;   w += (size_t)N * 4;
    int*   partials = (int*)w;   w += (size_t)256 * 4;
    int*   csr_off  = (int*)w;   w += (size_t)E * 4;
    float* psum     = (float*)w; w += (size_t)256 * HID * 4;
    float* pmax     = (float*)w; w += (size_t)256 * HID * 4;

    const int nb = (N + 255) / 256;
    const int nW = 4 * HID * HID;

    // weight bf16 split (once per launch)
    k_tobf16<<<(nW / 4 + 255) / 256, 256, 0, stream>>>(Wl, whiL, wloL, nW);
    k_tobf16<<<(nW / 4 + 255) / 256, 256, 0, stream>>>(Wr, whiR, wloR, nW);

    // CSR build
    k_zero_int<<<nb, 256, 0, stream>>>(counts, N);
    k_hist<<<(E + 255) / 256, 256, 0, stream>>>(dst, E, counts);
    k_scan_block<<<nb, 256, 0, stream>>>(counts, N, scanout, partials);
    k_scan_part<<<1, 256, 0, stream>>>(partials, nb);
    k_scan_add<<<nb, 256, 0, stream>>>(scanout, partials, N, E, rowptr, nextp);
    k_scatter<<<(E + 255) / 256, 256, 0, stream>>>(src, dst, E, nextp, csr_off);

    // embedding -> bf16 hi/lo (buffer A)
    k_embed<<<N, 128, 0, stream>>>(nf, W_emb, b_emb, hA, lA, N);

    dim3 lgrid((N + 127) / 128, 2);
    for (int i = 0; i < 4; i++) {
        // ping-pong: even layers read A write B, odd layers read B write A
        const unsigned short* inH = (i & 1) ? hB : hA;
        const unsigned short* inL = (i & 1) ? lB : lA;
        unsigned short* oH = (i & 1) ? hA : hB;
        unsigned short* oL = (i & 1) ? lA : lB;
        k_linear_mfma<<<lgrid, 512, 0, stream>>>(inH, inL,
                                                 whiL + (size_t)i * HID * HID, wloL + (size_t)i * HID * HID,
                                                 whiR + (size_t)i * HID * HID, wloR + (size_t)i * HID * HID,
                                                 bl + i * HID, br + i * HID, xlh, xrh, N);
        k_attn<<<(N + 3) / 4, 256, 0, stream>>>(xlh, xrh, rowptr, csr_off,
                                                att + i * HEADS * 32, bias + i * HID,
                                                inH, inL, oH, oL, xout,
                                                i > 0 ? 1 : 0, i < 3 ? 1 : 0, N);
    }

    k_reduce1<<<256, 128, 0, stream>>>(xout, N, psum, pmax);
    k_reduce2<<<1, 128, 0, stream>>>(psum, pmax, 256, out, 1.0f / N);
}